// Round 5
// baseline (533.543 us; speedup 1.0000x reference)
//
#include <hip/hip_runtime.h>

typedef unsigned short u16;
typedef unsigned int   u32;

using bf16x8 = __attribute__((ext_vector_type(8))) __bf16;
using f32x4  = __attribute__((ext_vector_type(4))) float;

__device__ __forceinline__ float bf2f(u16 h){ return __uint_as_float(((u32)h) << 16); }
__device__ __forceinline__ u16 f2bf(float f){
    u32 u = __float_as_uint(f);
    u32 r = u + 0x7FFFu + ((u >> 16) & 1u);   // round-to-nearest-even
    return (u16)(r >> 16);
}

// async global->LDS, 16B per lane; LDS dest = wave-uniform base + lane*16.
__device__ __forceinline__ void async16(const void* g, void* l){
    __builtin_amdgcn_global_load_lds(
        (const __attribute__((address_space(1))) unsigned int*)g,
        (__attribute__((address_space(3))) unsigned int*)l, 16, 0, 0);
}
__device__ __forceinline__ bf16x8 cvt8(uint4 v){
    union { uint4 u; bf16x8 b; } c; c.u = v; return c.b;
}

// ---------------------------------------------------------------------------
// Block 0: dtype probe. flags[0]=1 if floats bf16; flags[1]=mask dtype
// 0=u8,1=i32,2=bf16,3=f32.  Block 1: label grouping (slot_of_node, ovf_flag).
// ---------------------------------------------------------------------------
__global__ void probe_and_perm(const void* x, const void* masks, int* flags,
                               const int* labels, int* slot_of_node, int* ovf_flag)
{
    if (blockIdx.x == 0){
        int l = threadIdx.x;
        if (l < 64){
            const u16* hx = (const u16*)x;
            int e0 = (hx[l] >> 7) & 0xFF;
            int e1 = (hx[l + 64] >> 7) & 0xFF;
            unsigned long long b0 = __ballot(e0 >= 100 && e0 <= 140);
            unsigned long long b1 = __ballot(e1 >= 100 && e1 <= 140);
            int cnt = __popcll(b0) + __popcll(b1);
            const u32* w  = (const u32*)masks;
            const u16* hm = (const u16*)masks;
            u32 v = w[l];
            unsigned long long i32bad = __ballot(v > 1u);
            unsigned long long f32bad = __ballot(v != 0u && v != 0x3F800000u);
            u16 h0 = hm[l], h1 = hm[l + 64];
            unsigned long long bfbad =
                __ballot((h0 != 0 && h0 != 0x3F80) || (h1 != 0 && h1 != 0x3F80));
            if (l == 0){
                flags[0] = (cnt >= 100) ? 1 : 0;
                int md = 0;
                if (!i32bad) md = 1; else if (!f32bad) md = 3; else if (!bfbad) md = 2;
                flags[1] = md;
            }
        }
        return;
    }
    __shared__ int lab[300];
    __shared__ unsigned char sp[300];
    int t = threadIdx.x;
    if (t < 300) lab[t] = labels[t];
    __syncthreads();
    int r = 0;
    if (t < 300){
        int k = lab[t];
        for (int j = 0; j < t; j++) r += (lab[j] == k);
        sp[t] = (r >= 128) ? 1 : 0;
    }
    __syncthreads();
    if (t < 300){
        if (!sp[t]) slot_of_node[t] = lab[t] * 128 + r;
        else {
            int so = 0;
            for (int j = 0; j < t; j++) so += sp[j];
            slot_of_node[t] = 384 + so;
        }
    }
    if (t == 0){
        int tot = 0;
        for (int j = 0; j < 300; j++) tot += sp[j];
        *ovf_flag = tot;
    }
}

// ---------------------------------------------------------------------------
// Transpose + convert to bf16, 3 sources via blockIdx.z; zero-pads j >= J.
// ---------------------------------------------------------------------------
__global__ void trans_cvt_f3(const void* s0, const void* s1, const void* s2,
                             u16* dst, size_t dstride, int I, int J, int ldd,
                             const int* flags)
{
    __shared__ float tile[32][33];
    const void* src = (blockIdx.z == 0) ? s0 : (blockIdx.z == 1) ? s1 : s2;
    u16* d = dst + (size_t)blockIdx.z * dstride;
    int j0 = blockIdx.x * 32, i0 = blockIdx.y * 32;
    int tx = threadIdx.x, ty = threadIdx.y;
    bool isbf = (flags[0] != 0);
    #pragma unroll
    for (int s = 0; s < 32; s += 8){
        int i = i0 + ty + s, j = j0 + tx;
        float v = 0.f;
        if (j < J){
            size_t idx = (size_t)i * J + j;
            v = isbf ? bf2f(((const u16*)src)[idx]) : ((const float*)src)[idx];
        }
        tile[ty + s][tx] = v;
    }
    __syncthreads();
    #pragma unroll
    for (int s = 0; s < 32; s += 8){
        int j = j0 + ty + s, i = i0 + tx;
        d[(size_t)j * ldd + i] = f2bf(tile[tx][ty + s]);
    }
}

__global__ void pack_biases(const void* a0, const void* a1, const void* a2,
                            const void* c0, const void* c1, const void* c2,
                            float* b1f, float* b2f, const int* flags)
{
    int idx = blockIdx.x * 256 + threadIdx.x;
    if (idx >= 3072) return;
    int k = idx >> 10, r = idx & 1023;
    bool isbf = (flags[0] != 0);
    const void* p1 = (k == 0) ? a0 : (k == 1) ? a1 : a2;
    const void* p2 = (k == 0) ? c0 : (k == 1) ? c1 : c2;
    b1f[idx] = isbf ? bf2f(((const u16*)p1)[r]) : ((const float*)p1)[r];
    b2f[idx] = isbf ? bf2f(((const u16*)p2)[r]) : ((const float*)p2)[r];
}

// ---------------------------------------------------------------------------
// masks [P][NN] -> mfT[slot][p] bf16 {0,1} (rows permuted), fused popcount.
// ---------------------------------------------------------------------------
__global__ void trans_mask_count(const void* src, u16* dst,
                                 const int* slot_of_node, float* counts,
                                 const int* flags)
{
    constexpr int NN_ = 300, P_ = 40000, LDP = 40064;
    __shared__ u16 tile[128][33];    // [p_in][n_in]
    __shared__ int slt[32];
    const int p0 = blockIdx.x * 128, n0 = blockIdx.y * 32;
    const int tid = threadIdx.x;
    const int md = flags[1];
    if (tid < 32) slt[tid] = (n0 + tid < NN_) ? slot_of_node[n0 + tid] : -1;

    if (md == 0){
        const unsigned char* s8 = (const unsigned char*)src;
        const int tx = tid & 7, ty = tid >> 3;
        #pragma unroll
        for (int rep = 0; rep < 4; rep++){
            const int p = p0 + rep * 32 + ty;
            const int nb = n0 + tx * 4;
            u32 w = 0;
            if (p < P_){
                if (nb + 3 < NN_)
                    w = *(const u32*)(s8 + (size_t)p * NN_ + nb);
                else {
                    for (int b = 0; b < 4; b++)
                        if (nb + b < NN_)
                            w |= (u32)s8[(size_t)p * NN_ + nb + b] << (8 * b);
                }
            }
            #pragma unroll
            for (int b = 0; b < 4; b++)
                tile[rep * 32 + ty][tx * 4 + b] =
                    ((w >> (8 * b)) & 0xFFu) ? (u16)0x3F80 : (u16)0;
        }
    } else {
        #pragma unroll
        for (int it = 0; it < 16; it++){
            const int e = tid + it * 256;
            const int n_in = e & 31, p_in = e >> 5;
            const int p = p0 + p_in, n = n0 + n_in;
            u16 v = 0;
            if (p < P_ && n < NN_){
                size_t idx = (size_t)p * NN_ + n;
                bool on;
                if (md == 1)      on = ((const int*)src)[idx] != 0;
                else if (md == 2) on = ((const u16*)src)[idx] != 0;
                else              on = ((const float*)src)[idx] != 0.f;
                v = on ? (u16)0x3F80 : (u16)0;
            }
            tile[p_in][n_in] = v;
        }
    }
    __syncthreads();

    #pragma unroll
    for (int half = 0; half < 2; half++){
        const int row = tid >> 3;
        const int pos = (tid & 7) + half * 8;
        const int slot = slt[row];
        if (slot >= 0){
            union { u16 h[8]; uint4 v; } tmp;
            #pragma unroll
            for (int j = 0; j < 8; j++) tmp.h[j] = tile[pos * 8 + j][row];
            *reinterpret_cast<uint4*>(&dst[(size_t)slot * LDP + p0 + pos * 8]) = tmp.v;
        }
    }
    if (tid < 32){
        const int slot = slt[tid];
        if (slot >= 0){
            int c = 0;
            for (int p = 0; p < 128; p++) c += (tile[p][tid] != 0);
            if (c > 0) atomicAdd(&counts[slot], (float)c);
        }
    }
}

// ---------------------------------------------------------------------------
// FUSED L1 + mask-sum, v3: single-buffer 48KB LDS (3 blocks/CU), reordered
// 2-barrier K-loop (drain one body after issue), 768-block grid with XCD
// swizzle, mask fragments register-pipelined.
//   stage-1: H = relu(B1T[m-tile] . feat[p-tile]^T + b1)  (K=256)
//   repack:  H -> Hs[pc][128][32], XOR-swizzled by (m>>2)&3
//   stage-2: acc2[slot][m] += mask . H^T (K=128)
// MAP 0: grouped slots, sums=[3*128][1024]; MAP 1: overflow, sums=[128][3072].
// ---------------------------------------------------------------------------
template<int MAP>
__global__ __launch_bounds__(256, 3)
void fused_l1_mask(const u16* __restrict__ B1T, const u16* __restrict__ feat,
                   const u16* __restrict__ mfT, const float* __restrict__ b1f,
                   float* __restrict__ sums, const int* __restrict__ skipf)
{
    if constexpr (MAP == 1){ if (*skipf == 0) return; }
    constexpr int PPAD = 40064;
    __shared__ __align__(16) u16 As[4096];      // 8 KB
    __shared__ __align__(16) u16 Bs[4096];      // 8 KB
    __shared__ __align__(16) u16 Hs[16384];     // 32 KB  (total 48 KB)

    int bx, ts, te;
    if constexpr (MAP == 0){
        // 768 ids; the 8 m-subtiles of one (branch, p-chain) combo share a
        // residue mod 8 -> same XCD (round-robin dispatch heuristic).
        const int id = blockIdx.x;
        const int r = id & 7, qq = id >> 3;
        const int g = qq >> 3, sub = qq & 7;    // g: 0..11
        const int j = g * 8 + r;                // combo 0..95 = branch*32 + y
        bx = (j >> 5) * 8 + sub;                // branch*8 + sub
        const int y = j & 31;
        ts = y * 10; te = ts + 10; if (te > 313) te = 313;
        if (ts >= te) return;
    } else {
        bx = blockIdx.x;
        ts = blockIdx.y * 40; te = ts + 40; if (te > 313) te = 313;
        if (ts >= te) return;
    }
    const int m0 = bx * 128;
    const int srow = (MAP == 0) ? ((bx >> 3) * 128) : 384;

    const int tid = threadIdx.x;
    const int wave = tid >> 6, lane = tid & 63;
    const int wr = wave >> 1, wc = wave & 1;
    const int t = lane & 15, q = lane >> 4;

    float bv[4][4];
    #pragma unroll
    for (int mi = 0; mi < 4; mi++)
        #pragma unroll
        for (int i = 0; i < 4; i++)
            bv[mi][i] = b1f[m0 + wr*64 + mi*16 + q*4 + i];

    const int cr = lane >> 2, cp = lane & 3;
    const int ca = wave*2, cb = wave*2 + 1;
    const u16* gA0 = B1T + (size_t)(m0 + ca*16 + cr)*256 + cp*8;
    const u16* gA1 = B1T + (size_t)(m0 + cb*16 + cr)*256 + cp*8;
    const u16* gBb = feat + (size_t)(ca*16 + cr)*256 + cp*8;
    const u16* gBc = feat + (size_t)(cb*16 + cr)*256 + cp*8;
    u16* lA0 = As + ca*512;  u16* lA1 = As + cb*512;
    u16* lB0 = Bs + ca*512;  u16* lB1 = Bs + cb*512;
    const u16* mrow = mfT + (size_t)(srow + wr*64 + t) * PPAD;

    f32x4 acc2[4][4];
    #pragma unroll
    for (int a = 0; a < 4; a++)
        #pragma unroll
        for (int b = 0; b < 4; b++)
            #pragma unroll
            for (int e = 0; e < 4; e++) acc2[a][b][e] = 0.f;

    // prologue: stage (ts, kt=0)
    {
        const size_t pofs = (size_t)ts * 128 * 256;
        async16(gA0, lA0);
        async16(gA1, lA1);
        async16(gBb + pofs, lB0);
        async16(gBc + pofs, lB1);
    }

    for (int pt = ts; pt < te; ++pt){
        const int p0 = pt * 128;
        const size_t pofs = (size_t)p0 * 256;

        f32x4 acc1[4][4];
        #pragma unroll
        for (int a = 0; a < 4; a++)
            #pragma unroll
            for (int b = 0; b < 4; b++)
                #pragma unroll
                for (int e = 0; e < 4; e++) acc1[a][b][e] = 0.f;

        uint4 mcur[4], mnxt[4];

        #pragma unroll
        for (int kt = 0; kt < 8; ++kt){
            __syncthreads();            // drain staged loads for kt (issued 1 body ago)
            bf16x8 af[4], bg[4];
            #pragma unroll
            for (int mi = 0; mi < 4; mi++)
                af[mi] = *reinterpret_cast<const bf16x8*>(
                    &As[(wr*64 + mi*16 + t)*32 + q*8]);
            #pragma unroll
            for (int ni = 0; ni < 4; ni++)
                bg[ni] = *reinterpret_cast<const bf16x8*>(
                    &Bs[(wc*64 + ni*16 + t)*32 + q*8]);
            __syncthreads();            // all waves consumed As/Bs -> safe to refill
            if (kt < 7){
                const size_t ko = (size_t)(kt + 1) * 32;
                async16(gA0 + ko, lA0);
                async16(gA1 + ko, lA1);
                async16(gBb + pofs + ko, lB0);
                async16(gBc + pofs + ko, lB1);
            } else {
                if (pt + 1 < te){       // next p-tile kt=0, covered by stage-2
                    const size_t pofs2 = pofs + (size_t)128 * 256;
                    async16(gA0, lA0);
                    async16(gA1, lA1);
                    async16(gBb + pofs2, lB0);
                    async16(gBc + pofs2, lB1);
                }
                #pragma unroll
                for (int mi = 0; mi < 4; mi++)   // mask pc=0 fragments
                    mcur[mi] = *reinterpret_cast<const uint4*>(
                        mrow + (size_t)(mi*16)*PPAD + p0 + q*8);
            }
            #pragma unroll
            for (int mi = 0; mi < 4; mi++)
                #pragma unroll
                for (int ni = 0; ni < 4; ni++)
                    acc1[mi][ni] = __builtin_amdgcn_mfma_f32_16x16x32_bf16(
                        af[mi], bg[ni], acc1[mi][ni], 0, 0, 0);
        }

        // epilogue: bias+relu, H -> Hs with XOR swizzle ((m_l>>2)&3 == q).
        // Safe: all waves passed kt-loop barriers, so prior stage-2 reads done.
        #pragma unroll
        for (int mi = 0; mi < 4; mi++){
            #pragma unroll
            for (int i = 0; i < 4; i++){
                const int m_l = wr*64 + mi*16 + q*4 + i;
                const float bb = bv[mi][i];
                #pragma unroll
                for (int ni = 0; ni < 4; ni++){
                    const int p_l = wc*64 + ni*16 + t;
                    float v = acc1[mi][ni][i] + bb;
                    v = (v > 0.f) ? v : 0.f;
                    const int pc = p_l >> 5, pin = p_l & 31;
                    const int cg = (pin >> 3) ^ q;
                    Hs[pc*4096 + m_l*32 + cg*8 + (pin & 7)] = f2bf(v);
                }
            }
        }
        __syncthreads();

        // stage-2: acc2 += mask . H^T, K=128 in 4 chunks; mask pipelined
        #pragma unroll
        for (int pc = 0; pc < 4; ++pc){
            if (pc < 3){
                #pragma unroll
                for (int mi = 0; mi < 4; mi++)
                    mnxt[mi] = *reinterpret_cast<const uint4*>(
                        mrow + (size_t)(mi*16)*PPAD + p0 + (pc+1)*32 + q*8);
            }
            bf16x8 hb[4];
            #pragma unroll
            for (int ni = 0; ni < 4; ni++){
                const int row = wc*64 + ni*16 + t;
                hb[ni] = *reinterpret_cast<const bf16x8*>(
                    &Hs[pc*4096 + row*32 + ((q ^ (t >> 2)) * 8)]);
            }
            #pragma unroll
            for (int mi = 0; mi < 4; mi++)
                #pragma unroll
                for (int ni = 0; ni < 4; ni++)
                    acc2[mi][ni] = __builtin_amdgcn_mfma_f32_16x16x32_bf16(
                        cvt8(mcur[mi]), hb[ni], acc2[mi][ni], 0, 0, 0);
            if (pc < 3){
                #pragma unroll
                for (int mi = 0; mi < 4; mi++) mcur[mi] = mnxt[mi];
            }
        }
    }

    // dump accumulators (rows = slots, cols = m)
    #pragma unroll
    for (int mi = 0; mi < 4; mi++){
        #pragma unroll
        for (int i = 0; i < 4; i++){
            const int slot_l = wr*64 + mi*16 + q*4 + i;
            #pragma unroll
            for (int ni = 0; ni < 4; ni++){
                const int m_l = wc*64 + ni*16 + t;
                const float v = acc2[mi][ni][i];
                if constexpr (MAP == 0)
                    atomicAdd(sums + (size_t)((bx>>3)*128 + slot_l)*1024
                                   + (bx&7)*128 + m_l, v);
                else
                    atomicAdd(sums + (size_t)slot_l*3072 + bx*128 + m_l, v);
            }
        }
    }
}

// ---------------------------------------------------------------------------
// NT GEMM for the small L2 layers. MAP==3: batched over blockIdx.z (0..5);
// z>=3 uses A2/Cp2 (overflow) gated by skipf.
// ---------------------------------------------------------------------------
template<int BIAS_MODE, bool RELU, int OUT_MODE, int MAP>
__global__ __launch_bounds__(256)
void gemm_nt(const u16* __restrict__ A, int lda,
             const u16* __restrict__ B, int ldb,
             void* __restrict__ Cp, int ldc,
             const float* __restrict__ bias,
             int kIters, int kChunk,
             const int* __restrict__ skipf,
             long abatch, long bbatch, long cbatch, long bbias,
             const u16* __restrict__ A2, void* __restrict__ Cp2)
{
    __shared__ __align__(16) u16 sh[8192];
    u16* As = sh;
    u16* Bs = sh + 4096;

    const int tid  = threadIdx.x;
    const int wave = tid >> 6, lane = tid & 63;
    const int wr = wave >> 1, wc = wave & 1;
    const int t = lane & 15, q = lane >> 4;

    int m0, n0;
    if constexpr (MAP == 1){ m0 = blockIdx.x * 128; n0 = blockIdx.y * 128; }
    else { m0 = blockIdx.y * 128; n0 = blockIdx.x * 128; }

    size_t cofs = 0;
    int k0, k1;
    if constexpr (MAP == 3){
        const int bz = blockIdx.z;
        const int k = (bz >= 3) ? bz - 3 : bz;
        if (bz >= 3){
            if (*skipf == 0) return;
            A = A2; Cp = Cp2;
        }
        A += (size_t)k * (size_t)abatch;
        B += (size_t)k * (size_t)bbatch;
        bias += (size_t)k * (size_t)bbias;
        cofs = (size_t)k * (size_t)cbatch;
        k0 = 0; k1 = kIters;
    } else {
        if (skipf && *skipf == 0) return;
        k0 = blockIdx.z * kChunk;
        k1 = k0 + kChunk; if (k1 > kIters) k1 = kIters;
        if (k0 >= k1) return;
    }

    const int cr = lane >> 2, cp = lane & 3;
    const int ca = wave * 2, cb = wave * 2 + 1;
    const u16* gA0 = A + (size_t)(m0 + ca * 16 + cr) * lda + cp * 8;
    const u16* gA1 = A + (size_t)(m0 + cb * 16 + cr) * lda + cp * 8;
    const u16* gB0 = B + (size_t)(n0 + ca * 16 + cr) * ldb + cp * 8;
    const u16* gB1 = B + (size_t)(n0 + cb * 16 + cr) * ldb + cp * 8;
    u16* lA0 = As + ca * 512;  u16* lA1 = As + cb * 512;
    u16* lB0 = Bs + ca * 512;  u16* lB1 = Bs + cb * 512;

    f32x4 acc[4][4];
    #pragma unroll
    for (int a = 0; a < 4; a++)
        #pragma unroll
        for (int b = 0; b < 4; b++)
            #pragma unroll
            for (int e = 0; e < 4; e++) acc[a][b][e] = 0.f;

    for (int kt = k0; kt < k1; ++kt){
        __syncthreads();
        const size_t ko = (size_t)kt * 32;
        async16(gA0 + ko, lA0);
        async16(gA1 + ko, lA1);
        async16(gB0 + ko, lB0);
        async16(gB1 + ko, lB1);
        __syncthreads();
        bf16x8 af[4], bg[4];
        #pragma unroll
        for (int mi = 0; mi < 4; mi++)
            af[mi] = *reinterpret_cast<const bf16x8*>(
                &As[(wr * 64 + mi * 16 + t) * 32 + q * 8]);
        #pragma unroll
        for (int ni = 0; ni < 4; ni++)
            bg[ni] = *reinterpret_cast<const bf16x8*>(
                &Bs[(wc * 64 + ni * 16 + t) * 32 + q * 8]);
        #pragma unroll
        for (int mi = 0; mi < 4; mi++)
            #pragma unroll
            for (int ni = 0; ni < 4; ni++)
                acc[mi][ni] = __builtin_amdgcn_mfma_f32_16x16x32_bf16(
                    af[mi], bg[ni], acc[mi][ni], 0, 0, 0);
    }

    #pragma unroll
    for (int mi = 0; mi < 4; mi++){
        #pragma unroll
        for (int i = 0; i < 4; i++){
            int m = m0 + wr * 64 + mi * 16 + q * 4 + i;
            float bm = 0.f;
            if constexpr (BIAS_MODE == 1) bm = bias[m];
            #pragma unroll
            for (int ni = 0; ni < 4; ni++){
                int n = n0 + wc * 64 + ni * 16 + t;
                float v = acc[mi][ni][i] + bm;
                if constexpr (BIAS_MODE == 2) v += bias[n];
                if constexpr (RELU) v = (v > 0.f) ? v : 0.f;
                size_t ci = cofs + (size_t)m * ldc + n;
                if constexpr (OUT_MODE == 2) atomicAdd(((float*)Cp) + ci, v);
                else                         ((float*)Cp)[ci] = v;
            }
        }
    }
}

// b<384: means[slot][q] = sums3[slot][q]/counts[slot]
// b>=384: overflow means for all 3 branches of each ovf slot.
__global__ void build_means_all(const float* sums3, const float* sumsOvf,
                                const float* counts, u16* means, u16* meansOv)
{
    int b = blockIdx.x;                  // 0..767
    const float* src;
    u16* dst;
    float c;
    if (b < 384){
        c = counts[b];
        src = sums3 + (size_t)b * 1024;
        dst = means + (size_t)b * 1024;
    } else {
        int e = b - 384;
        int bb = e >> 7, os = e & 127;
        c = counts[384 + os];
        src = sumsOvf + (size_t)os * 3072 + (size_t)bb * 1024;
        dst = meansOv + (size_t)e * 1024;
    }
    float inv = (c > 0.f) ? 1.f / c : 0.f;
    #pragma unroll
    for (int i = 0; i < 4; i++){
        int qi = threadIdx.x + i * 256;
        dst[qi] = f2bf(src[qi] * inv);
    }
}

__global__ void select_out(const float* outA, const float* outOvf,
                           const int* labels, const int* slot_of_node,
                           void* dout, const int* flags)
{
    int idx = blockIdx.x * 256 + threadIdx.x;   // < 300*1024
    int n = idx >> 10, r = idx & 1023;
    int slot = slot_of_node[n];
    float v;
    if (slot < 384) v = outA[(size_t)slot * 1024 + r];
    else {
        int k = labels[n];
        v = outOvf[((size_t)k * 128 + (slot - 384)) * 1024 + r];
    }
    if (flags[0]) ((u16*)dout)[idx] = f2bf(v);
    else          ((float*)dout)[idx] = v;
}

// ---------------------------------------------------------------------------
extern "C" void kernel_launch(void* const* d_in, const int* in_sizes, int n_in,
                              void* d_out, int out_size, void* d_ws, size_t ws_size,
                              hipStream_t stream)
{
    constexpr int C = 256, R = 1024, NN = 300, P = 40000;
    constexpr int PPAD = 40064;          // 313 * 128
    constexpr int M1 = 3 * R;            // 3072 L1 rows (branch-major)
    constexpr int SLOTS = 512;           // 3*128 grouped + 128 overflow

    const void* x      = d_in[0];
    const void* masks  = d_in[1];
    const int*  labels = (const int*)d_in[2];
    const void* W1[3] = { d_in[3], d_in[7],  d_in[11] };
    const void* B1[3] = { d_in[4], d_in[8],  d_in[12] };
    const void* W2[3] = { d_in[5], d_in[9],  d_in[13] };
    const void* B2[3] = { d_in[6], d_in[10], d_in[14] };
    (void)in_sizes; (void)n_in; (void)out_size; (void)ws_size;

    char* ws = (char*)d_ws;
    size_t off = 0;
    auto alloc = [&](size_t b)->size_t {
        size_t o = off; off += (b + 255) & ~(size_t)255; return o;
    };

    int*   flags   = (int*)  (ws + alloc(256));
    int*   slotmap = (int*)  (ws + alloc(384 * 4));
    int*   ovfflag = (int*)  (ws + alloc(256));
    u16*   feat    = (u16*)  (ws + alloc((size_t)PPAD * C * 2));    // [p][c]
    u16*   B1T     = (u16*)  (ws + alloc((size_t)M1 * C * 2));      // [m][c]
    float* b1f     = (float*)(ws + alloc((size_t)M1 * 4));
    float* b2f     = (float*)(ws + alloc((size_t)M1 * 4));
    u16*   mfT     = (u16*)  (ws + alloc((size_t)SLOTS * PPAD * 2));// [slot][p]
    // contiguous zero region: sums3 | sumsOvf | counts
    float* sums3   = (float*)(ws + alloc((size_t)384 * 1024 * 4));
    float* sumsOvf = (float*)(ws + alloc((size_t)128 * M1 * 4));
    float* counts  = (float*)(ws + alloc((size_t)SLOTS * 4));
    u16*   means   = (u16*)  (ws + alloc((size_t)384 * R * 2));
    u16*   meansOv = (u16*)  (ws + alloc((size_t)384 * R * 2));
    u16*   W2T     = (u16*)  (ws + alloc((size_t)3 * R * R * 2));
    float* outA    = (float*)(ws + alloc((size_t)384 * R * 4));
    float* outOvf  = (float*)(ws + alloc((size_t)384 * R * 4));

    probe_and_perm<<<2, 320, 0, stream>>>(x, masks, flags, labels, slotmap, ovfflag);
    hipMemsetAsync(mfT, 0, (size_t)SLOTS * PPAD * 2, stream);
    hipMemsetAsync(sums3, 0,
        (size_t)384 * 1024 * 4 + (size_t)128 * M1 * 4 + (size_t)SLOTS * 4, stream);

    trans_cvt_f3<<<dim3(PPAD / 32, C / 32, 1), dim3(32, 8), 0, stream>>>(
        x, x, x, feat, 0, C, P, C, flags);
    trans_cvt_f3<<<dim3(R / 32, C / 32, 3), dim3(32, 8), 0, stream>>>(
        W1[0], W1[1], W1[2], B1T, (size_t)R * C, C, R, C, flags);
    trans_cvt_f3<<<dim3(R / 32, R / 32, 3), dim3(32, 8), 0, stream>>>(
        W2[0], W2[1], W2[2], W2T, (size_t)R * R, R, R, R, flags);
    pack_biases<<<(3 * R + 255) / 256, 256, 0, stream>>>(
        B1[0], B1[1], B1[2], B2[0], B2[1], B2[2], b1f, b2f, flags);
    trans_mask_count<<<dim3(PPAD / 128, 384 / 32), 256, 0, stream>>>(
        masks, mfT, slotmap, counts, flags);

    // fused L1 + mask-sum: 768 blocks = 3/CU x 256 CUs exactly
    fused_l1_mask<0><<<768, 256, 0, stream>>>(
        B1T, feat, mfT, b1f, sums3, nullptr);
    // overflow path (skipped unless some label has > 128 nodes)
    fused_l1_mask<1><<<dim3(24, 8), 256, 0, stream>>>(
        B1T, feat, mfT, b1f, sumsOvf, ovfflag);

    build_means_all<<<768, 256, 0, stream>>>(sums3, sumsOvf, counts, means, meansOv);

    // L2 on means: z=0..2 normal branches, z=3..5 overflow (flag-gated)
    gemm_nt<2, false, 0, 3>
        <<<dim3(R / 128, 1, 6), 256, 0, stream>>>(
            means, R, W2T, R, outA, R, b2f,
            R / 32, R / 32, ovfflag,
            (long)128 * R, (long)R * R, (long)128 * R, (long)R,
            meansOv, outOvf);

    select_out<<<(NN * R) / 256, 256, 0, stream>>>(
        outA, outOvf, labels, slotmap, d_out, flags);
}

// Round 6
// 443.914 us; speedup vs baseline: 1.2019x; 1.2019x over previous
//
#include <hip/hip_runtime.h>

typedef unsigned short u16;
typedef unsigned int   u32;

using bf16x8 = __attribute__((ext_vector_type(8))) __bf16;
using f32x4  = __attribute__((ext_vector_type(4))) float;

__device__ __forceinline__ float bf2f(u16 h){ return __uint_as_float(((u32)h) << 16); }
__device__ __forceinline__ u16 f2bf(float f){
    u32 u = __float_as_uint(f);
    u32 r = u + 0x7FFFu + ((u >> 16) & 1u);   // round-to-nearest-even
    return (u16)(r >> 16);
}

// async global->LDS, 16B per lane; LDS dest = wave-uniform base + lane*16.
__device__ __forceinline__ void async16(const void* g, void* l){
    __builtin_amdgcn_global_load_lds(
        (const __attribute__((address_space(1))) unsigned int*)g,
        (__attribute__((address_space(3))) unsigned int*)l, 16, 0, 0);
}
__device__ __forceinline__ bf16x8 cvt8(uint4 v){
    union { uint4 u; bf16x8 b; } c; c.u = v; return c.b;
}

// ---------------------------------------------------------------------------
// Block 0: dtype probe. flags[0]=1 if floats bf16; flags[1]=mask dtype
// 0=u8,1=i32,2=bf16,3=f32.
// Block 1: label grouping: slot_of_node[n] = label*128+rank (<128) else
// 384+ovf_rank; node_of_slot inverse (-1 = empty); ovf_flag = #overflow.
// ---------------------------------------------------------------------------
__global__ void probe_and_perm(const void* x, const void* masks, int* flags,
                               const int* labels, int* slot_of_node,
                               int* node_of_slot, int* ovf_flag)
{
    if (blockIdx.x == 0){
        int l = threadIdx.x;
        if (l < 64){
            const u16* hx = (const u16*)x;
            int e0 = (hx[l] >> 7) & 0xFF;
            int e1 = (hx[l + 64] >> 7) & 0xFF;
            unsigned long long b0 = __ballot(e0 >= 100 && e0 <= 140);
            unsigned long long b1 = __ballot(e1 >= 100 && e1 <= 140);
            int cnt = __popcll(b0) + __popcll(b1);
            const u32* w  = (const u32*)masks;
            const u16* hm = (const u16*)masks;
            u32 v = w[l];
            unsigned long long i32bad = __ballot(v > 1u);
            unsigned long long f32bad = __ballot(v != 0u && v != 0x3F800000u);
            u16 h0 = hm[l], h1 = hm[l + 64];
            unsigned long long bfbad =
                __ballot((h0 != 0 && h0 != 0x3F80) || (h1 != 0 && h1 != 0x3F80));
            if (l == 0){
                flags[0] = (cnt >= 100) ? 1 : 0;
                int md = 0;
                if (!i32bad) md = 1; else if (!f32bad) md = 3; else if (!bfbad) md = 2;
                flags[1] = md;
            }
        }
        return;
    }
    __shared__ int lab[300];
    __shared__ unsigned char sp[300];
    int t = threadIdx.x;                      // 320 threads
    for (int idx = t; idx < 512; idx += 320) node_of_slot[idx] = -1;
    if (t < 300) lab[t] = labels[t];
    __syncthreads();
    int r = 0;
    if (t < 300){
        int k = lab[t];
        for (int j = 0; j < t; j++) r += (lab[j] == k);
        sp[t] = (r >= 128) ? 1 : 0;
    }
    __syncthreads();
    if (t < 300){
        int slot;
        if (!sp[t]) slot = lab[t] * 128 + r;
        else {
            int so = 0;
            for (int j = 0; j < t; j++) so += sp[j];
            slot = 384 + so;
        }
        slot_of_node[t] = slot;
        node_of_slot[slot] = t;
    }
    if (t == 0){
        int tot = 0;
        for (int j = 0; j < 300; j++) tot += sp[j];
        *ovf_flag = tot;
    }
}

// ---------------------------------------------------------------------------
// One flat-grid prep kernel: feat transpose (x -> [p][c]), B1T (W1 -> [m][c]),
// W2T (W2 -> [k][r][q]), and bias packing. All bf16-convert, zero-pad j >= J.
// ---------------------------------------------------------------------------
__global__ void prep_combo(const void* x,
    const void* w10, const void* w11, const void* w12,
    const void* w20, const void* w21, const void* w22,
    const void* bb10, const void* bb11, const void* bb12,
    const void* bb20, const void* bb21, const void* bb22,
    u16* feat, u16* B1T, u16* W2T, float* b1f, float* b2f, const int* flags)
{
    __shared__ float tile[32][33];
    const int id = blockIdx.x;
    const bool isbf = (flags[0] != 0);
    const int tid = threadIdx.x;
    const int tx = tid & 31, ty = tid >> 5;

    const void* src; u16* d; int I, J, ldd, i0, j0;
    if (id < 10016){
        int fx = id % 1252, fy = id / 1252;
        src = x; d = feat; I = 256; J = 40000; ldd = 256;
        j0 = fx * 32; i0 = fy * 32;
    } else if (id < 10016 + 768){
        int idx = id - 10016;
        int z = idx / 256, r2 = idx % 256;
        src = (z == 0) ? w10 : (z == 1) ? w11 : w12;
        d = B1T + (size_t)z * 1024 * 256;
        I = 256; J = 1024; ldd = 256;
        j0 = (r2 % 32) * 32; i0 = (r2 / 32) * 32;
    } else if (id < 10016 + 768 + 3072){
        int idx = id - 10016 - 768;
        int z = idx / 1024, r2 = idx % 1024;
        src = (z == 0) ? w20 : (z == 1) ? w21 : w22;
        d = W2T + (size_t)z * 1024 * 1024;
        I = 1024; J = 1024; ldd = 1024;
        j0 = (r2 % 32) * 32; i0 = (r2 / 32) * 32;
    } else {
        int idx = (id - 10016 - 768 - 3072) * 256 + tid;
        if (idx < 3072){
            int k = idx >> 10, r2 = idx & 1023;
            const void* p1 = (k == 0) ? bb10 : (k == 1) ? bb11 : bb12;
            const void* p2 = (k == 0) ? bb20 : (k == 1) ? bb21 : bb22;
            b1f[idx] = isbf ? bf2f(((const u16*)p1)[r2]) : ((const float*)p1)[r2];
            b2f[idx] = isbf ? bf2f(((const u16*)p2)[r2]) : ((const float*)p2)[r2];
        }
        return;
    }
    #pragma unroll
    for (int s = 0; s < 32; s += 8){
        int i = i0 + ty + s, j = j0 + tx;
        float v = 0.f;
        if (j < J){
            size_t ix = (size_t)i * J + j;
            v = isbf ? bf2f(((const u16*)src)[ix]) : ((const float*)src)[ix];
        }
        tile[ty + s][tx] = v;
    }
    __syncthreads();
    #pragma unroll
    for (int s = 0; s < 32; s += 8){
        int j = j0 + ty + s, i = i0 + tx;
        d[(size_t)j * ldd + i] = f2bf(tile[tx][ty + s]);
    }
}

// ---------------------------------------------------------------------------
// masks [P][NN] -> mfT[slot][p] bf16 {0,1} (rows permuted), fused popcount.
// ---------------------------------------------------------------------------
__global__ void trans_mask_count(const void* src, u16* dst,
                                 const int* slot_of_node, float* counts,
                                 const int* flags)
{
    constexpr int NN_ = 300, P_ = 40000, LDP = 40064;
    __shared__ u16 tile[128][33];    // [p_in][n_in]
    __shared__ int slt[32];
    const int p0 = blockIdx.x * 128, n0 = blockIdx.y * 32;
    const int tid = threadIdx.x;
    const int md = flags[1];
    if (tid < 32) slt[tid] = (n0 + tid < NN_) ? slot_of_node[n0 + tid] : -1;

    if (md == 0){
        const unsigned char* s8 = (const unsigned char*)src;
        const int tx = tid & 7, ty = tid >> 3;
        #pragma unroll
        for (int rep = 0; rep < 4; rep++){
            const int p = p0 + rep * 32 + ty;
            const int nb = n0 + tx * 4;
            u32 w = 0;
            if (p < P_){
                if (nb + 3 < NN_)
                    w = *(const u32*)(s8 + (size_t)p * NN_ + nb);
                else {
                    for (int b = 0; b < 4; b++)
                        if (nb + b < NN_)
                            w |= (u32)s8[(size_t)p * NN_ + nb + b] << (8 * b);
                }
            }
            #pragma unroll
            for (int b = 0; b < 4; b++)
                tile[rep * 32 + ty][tx * 4 + b] =
                    ((w >> (8 * b)) & 0xFFu) ? (u16)0x3F80 : (u16)0;
        }
    } else {
        #pragma unroll
        for (int it = 0; it < 16; it++){
            const int e = tid + it * 256;
            const int n_in = e & 31, p_in = e >> 5;
            const int p = p0 + p_in, n = n0 + n_in;
            u16 v = 0;
            if (p < P_ && n < NN_){
                size_t idx = (size_t)p * NN_ + n;
                bool on;
                if (md == 1)      on = ((const int*)src)[idx] != 0;
                else if (md == 2) on = ((const u16*)src)[idx] != 0;
                else              on = ((const float*)src)[idx] != 0.f;
                v = on ? (u16)0x3F80 : (u16)0;
            }
            tile[p_in][n_in] = v;
        }
    }
    __syncthreads();

    #pragma unroll
    for (int half = 0; half < 2; half++){
        const int row = tid >> 3;
        const int pos = (tid & 7) + half * 8;
        const int slot = slt[row];
        if (slot >= 0){
            union { u16 h[8]; uint4 v; } tmp;
            #pragma unroll
            for (int j = 0; j < 8; j++) tmp.h[j] = tile[pos * 8 + j][row];
            *reinterpret_cast<uint4*>(&dst[(size_t)slot * LDP + p0 + pos * 8]) = tmp.v;
        }
    }
    if (tid < 32){
        const int slot = slt[tid];
        if (slot >= 0){
            int c = 0;
            for (int p = 0; p < 128; p++) c += (tile[p][tid] != 0);
            if (c > 0) atomicAdd(&counts[slot], (float)c);
        }
    }
}

// ---------------------------------------------------------------------------
// FUSED L1 + mask-sum v6: barrier-free K-loop.
//  - B1T m-panel (64 KB) loaded to LDS ONCE per block (no per-kt A staging).
//  - feat B-fragments load global->VGPR (dwordx4) with +1-kt pipelining;
//    the stage-1 K-loop contains NO __syncthreads at all.
//  - Hs 16 KB; stage-2 runs in two pc-parity halves -> 4 cheap barriers/ptile.
//  - LDS 80 KB, __launch_bounds__(256,2): 2 blocks/CU, no VGPR spill.
// MAP 0: grouped slots, sums=[3*128][1024], 512-block XCD-swizzled grid.
// MAP 1: overflow slots, sums=[128][3072]; early-out when no overflow.
// ---------------------------------------------------------------------------
template<int MAP>
__global__ __launch_bounds__(256, 2)
void fused_l1_mask(const u16* __restrict__ B1T, const u16* __restrict__ feat,
                   const u16* __restrict__ mfT, const float* __restrict__ b1f,
                   float* __restrict__ sums, const int* __restrict__ skipf)
{
    if constexpr (MAP == 1){ if (*skipf == 0) return; }
    constexpr int PPAD = 40064;
    __shared__ __align__(16) u16 As[32768];   // [kt][128][32]  64 KB
    __shared__ __align__(16) u16 Hs[8192];    // [lc][128][32]  16 KB

    int bx, ts, te;
    if constexpr (MAP == 0){
        // id = 64*g + 8*s + r ; combo = 8g + r (branch*21 + y), sub = s.
        // The 8 subtiles of a combo share id%8 -> same XCD (round-robin).
        const int id = blockIdx.x;
        const int r = id & 7, s = (id >> 3) & 7, g = id >> 6;
        const int combo = g * 8 + r;
        if (combo >= 63) return;
        const int branch = combo / 21, y = combo % 21;
        bx = branch * 8 + s;
        ts = y * 15; te = ts + 15; if (te > 313) te = 313;
    } else {
        bx = blockIdx.x;
        ts = blockIdx.y * 40; te = ts + 40; if (te > 313) te = 313;
        if (ts >= te) return;
    }
    const int m0 = bx * 128;
    const int srow = (MAP == 0) ? ((bx >> 3) * 128) : 384;

    const int tid = threadIdx.x;
    const int wave = tid >> 6, lane = tid & 63;
    const int wr = wave >> 1, wc = wave & 1;
    const int t = lane & 15, q = lane >> 4;

    // stage B1T panel into As once: per wave per kt, 2 chunks of 16 rows x 64B
    const int cr = lane >> 2, cp = lane & 3;
    const int ca = wave * 2, cb = wave * 2 + 1;
    {
        const u16* gA0 = B1T + (size_t)(m0 + ca * 16 + cr) * 256 + cp * 8;
        const u16* gA1 = B1T + (size_t)(m0 + cb * 16 + cr) * 256 + cp * 8;
        #pragma unroll
        for (int kt = 0; kt < 8; kt++){
            async16(gA0 + kt * 32, &As[kt * 4096 + ca * 512]);
            async16(gA1 + kt * 32, &As[kt * 4096 + cb * 512]);
        }
    }

    float bv[4][4];
    #pragma unroll
    for (int mi = 0; mi < 4; mi++)
        #pragma unroll
        for (int i = 0; i < 4; i++)
            bv[mi][i] = b1f[m0 + wr*64 + mi*16 + q*4 + i];

    const u16* mrow = mfT + (size_t)(srow + wr*64 + t) * PPAD;
    const u16* gF = feat + (size_t)(wc*64 + t) * 256 + q * 8;  // + p*256 + kt*32

    f32x4 acc2[4][4];
    #pragma unroll
    for (int a = 0; a < 4; a++)
        #pragma unroll
        for (int b = 0; b < 4; b++)
            #pragma unroll
            for (int e = 0; e < 4; e++) acc2[a][b][e] = 0.f;

    // prefetch feat frags for (ts, kt=0); drained by the As barrier below
    uint4 bgv[4];
    #pragma unroll
    for (int ni = 0; ni < 4; ni++)
        bgv[ni] = *reinterpret_cast<const uint4*>(
            gF + (size_t)(ts * 128 + ni * 16) * 256);

    __syncthreads();   // As resident + bgv arrived

    for (int pt = ts; pt < te; ++pt){
        const int p0 = pt * 128;

        f32x4 acc1[4][4];
        #pragma unroll
        for (int a = 0; a < 4; a++)
            #pragma unroll
            for (int b = 0; b < 4; b++)
                #pragma unroll
                for (int e = 0; e < 4; e++) acc1[a][b][e] = 0.f;

        uint4 ma[2][4];

        // ---- stage-1 K-loop: NO barriers ----
        #pragma unroll
        for (int kt = 0; kt < 8; ++kt){
            bf16x8 af[4];
            #pragma unroll
            for (int mi = 0; mi < 4; mi++)
                af[mi] = *reinterpret_cast<const bf16x8*>(
                    &As[kt*4096 + (wr*64 + mi*16 + t)*32 + q*8]);
            uint4 bgn[4];
            if (kt < 7){
                #pragma unroll
                for (int ni = 0; ni < 4; ni++)
                    bgn[ni] = *reinterpret_cast<const uint4*>(
                        gF + (size_t)(p0 + ni*16) * 256 + (kt + 1) * 32);
            } else {
                #pragma unroll
                for (int mi = 0; mi < 4; mi++){   // mask frags, even pcs {0,2}
                    ma[0][mi] = *reinterpret_cast<const uint4*>(
                        mrow + (size_t)(mi*16)*PPAD + p0 + 0*32 + q*8);
                    ma[1][mi] = *reinterpret_cast<const uint4*>(
                        mrow + (size_t)(mi*16)*PPAD + p0 + 2*32 + q*8);
                }
            }
            #pragma unroll
            for (int mi = 0; mi < 4; mi++)
                #pragma unroll
                for (int ni = 0; ni < 4; ni++)
                    acc1[mi][ni] = __builtin_amdgcn_mfma_f32_16x16x32_bf16(
                        af[mi], cvt8(bgv[ni]), acc1[mi][ni], 0, 0, 0);
            if (kt < 7){
                #pragma unroll
                for (int ni = 0; ni < 4; ni++) bgv[ni] = bgn[ni];
            }
        }

        // ---- half A: even pc chunks {0 (wc0), 2 (wc1)}, lc = wc ----
        #pragma unroll
        for (int mi = 0; mi < 4; mi++){
            #pragma unroll
            for (int i = 0; i < 4; i++){
                const int m_l = wr*64 + mi*16 + q*4 + i;
                const float bb = bv[mi][i];
                #pragma unroll
                for (int ni = 0; ni < 2; ni++){
                    const int pin = ni*16 + t;
                    float v = acc1[mi][ni][i] + bb;
                    v = (v > 0.f) ? v : 0.f;
                    const int cg = (pin >> 3) ^ q;
                    Hs[wc*4096 + m_l*32 + cg*8 + (pin & 7)] = f2bf(v);
                }
            }
        }
        __syncthreads();
        #pragma unroll
        for (int lc = 0; lc < 2; lc++){
            bf16x8 hb[4];
            #pragma unroll
            for (int ni = 0; ni < 4; ni++)
                hb[ni] = *reinterpret_cast<const bf16x8*>(
                    &Hs[lc*4096 + (wc*64 + ni*16 + t)*32 + ((q ^ (t >> 2)) * 8)]);
            #pragma unroll
            for (int mi = 0; mi < 4; mi++)
                #pragma unroll
                for (int ni = 0; ni < 4; ni++)
                    acc2[mi][ni] = __builtin_amdgcn_mfma_f32_16x16x32_bf16(
                        cvt8(ma[lc][mi]), hb[ni], acc2[mi][ni], 0, 0, 0);
        }
        __syncthreads();

        // ---- half B: odd pc chunks {1 (wc0), 3 (wc1)}, lc = wc ----
        #pragma unroll
        for (int mi = 0; mi < 4; mi++){
            #pragma unroll
            for (int i = 0; i < 4; i++){
                const int m_l = wr*64 + mi*16 + q*4 + i;
                const float bb = bv[mi][i];
                #pragma unroll
                for (int ni = 2; ni < 4; ni++){
                    const int pin = (ni & 1)*16 + t;
                    float v = acc1[mi][ni][i] + bb;
                    v = (v > 0.f) ? v : 0.f;
                    const int cg = (pin >> 3) ^ q;
                    Hs[wc*4096 + m_l*32 + cg*8 + (pin & 7)] = f2bf(v);
                }
            }
        }
        // prefetch next p-tile feat kt=0 + odd-pc mask frags (drained at barrier)
        if (pt + 1 < te){
            #pragma unroll
            for (int ni = 0; ni < 4; ni++)
                bgv[ni] = *reinterpret_cast<const uint4*>(
                    gF + (size_t)((pt + 1) * 128 + ni * 16) * 256);
        }
        #pragma unroll
        for (int mi = 0; mi < 4; mi++){
            ma[0][mi] = *reinterpret_cast<const uint4*>(
                mrow + (size_t)(mi*16)*PPAD + p0 + 1*32 + q*8);
            ma[1][mi] = *reinterpret_cast<const uint4*>(
                mrow + (size_t)(mi*16)*PPAD + p0 + 3*32 + q*8);
        }
        __syncthreads();
        #pragma unroll
        for (int lc = 0; lc < 2; lc++){
            bf16x8 hb[4];
            #pragma unroll
            for (int ni = 0; ni < 4; ni++)
                hb[ni] = *reinterpret_cast<const bf16x8*>(
                    &Hs[lc*4096 + (wc*64 + ni*16 + t)*32 + ((q ^ (t >> 2)) * 8)]);
            #pragma unroll
            for (int mi = 0; mi < 4; mi++)
                #pragma unroll
                for (int ni = 0; ni < 4; ni++)
                    acc2[mi][ni] = __builtin_amdgcn_mfma_f32_16x16x32_bf16(
                        cvt8(ma[lc][mi]), hb[ni], acc2[mi][ni], 0, 0, 0);
        }
        __syncthreads();   // protect Hs before next p-tile's writes
    }

    // dump accumulators (rows = slots, cols = m)
    #pragma unroll
    for (int mi = 0; mi < 4; mi++){
        #pragma unroll
        for (int i = 0; i < 4; i++){
            const int slot_l = wr*64 + mi*16 + q*4 + i;
            #pragma unroll
            for (int ni = 0; ni < 4; ni++){
                const int m_l = wc*64 + ni*16 + t;
                const float v = acc2[mi][ni][i];
                if constexpr (MAP == 0)
                    atomicAdd(sums + (size_t)((bx>>3)*128 + slot_l)*1024
                                   + (bx&7)*128 + m_l, v);
                else
                    atomicAdd(sums + (size_t)slot_l*3072 + bx*128 + m_l, v);
            }
        }
    }
}

// ---------------------------------------------------------------------------
// L2 GEMM, fully fused: A = sums (fp32) scaled by 1/count and converted to
// bf16 during LDS staging (means never materialized); B = W2T; epilogue adds
// bias and scatters straight to d_out via node_of_slot (select_out fused).
// blockIdx.z: 0..2 normal branches, 3..5 overflow branches (flag-gated).
// ---------------------------------------------------------------------------
__global__ __launch_bounds__(256)
void l2_gemm(const float* __restrict__ sums3, const float* __restrict__ sumsOvf,
             const float* __restrict__ counts, const u16* __restrict__ W2T,
             const float* __restrict__ b2f, const int* __restrict__ node_of_slot,
             const int* __restrict__ labels, const int* __restrict__ ovfflag,
             void* __restrict__ dout, const int* __restrict__ flags)
{
    const int z = blockIdx.z;
    const int k = (z >= 3) ? z - 3 : z;
    if (z >= 3 && *ovfflag == 0) return;
    const int n0 = blockIdx.x * 128;

    const float* Arow; int astride, slotbase;
    if (z < 3){ Arow = sums3 + (size_t)z * 128 * 1024; astride = 1024; slotbase = z * 128; }
    else      { Arow = sumsOvf + (size_t)k * 1024;     astride = 3072; slotbase = 384; }

    __shared__ __align__(16) u16 As[4096];
    __shared__ __align__(16) u16 Bs[4096];
    __shared__ float invc[128];

    const int tid  = threadIdx.x;
    const int wave = tid >> 6, lane = tid & 63;
    const int wr = wave >> 1, wc = wave & 1;
    const int t = lane & 15, q = lane >> 4;

    if (tid < 128){
        float c = counts[slotbase + tid];
        invc[tid] = (c > 0.f) ? 1.f / c : 0.f;
    }

    const u16* Bsrc = W2T + (size_t)k * 1024 * 1024;
    const int cr = lane >> 2, cp = lane & 3;
    const int ca = wave * 2, cb = wave * 2 + 1;
    const u16* gB0 = Bsrc + (size_t)(n0 + ca * 16 + cr) * 1024 + cp * 8;
    const u16* gB1 = Bsrc + (size_t)(n0 + cb * 16 + cr) * 1024 + cp * 8;

    f32x4 acc[4][4];
    #pragma unroll
    for (int a = 0; a < 4; a++)
        #pragma unroll
        for (int b = 0; b < 4; b++)
            #pragma unroll
            for (int e = 0; e < 4; e++) acc[a][b][e] = 0.f;

    for (int kt = 0; kt < 32; ++kt){
        __syncthreads();
        // A staging: fp32 -> scale -> bf16
        #pragma unroll
        for (int rep = 0; rep < 2; rep++){
            int idx = tid + rep * 256;
            int row = idx >> 2, quarter = idx & 3;
            const float4* src = reinterpret_cast<const float4*>(
                Arow + (size_t)row * astride + kt * 32 + quarter * 8);
            float4 v0 = src[0], v1 = src[1];
            float s = invc[row];
            union { u16 h[8]; uint4 v; } pk;
            pk.h[0] = f2bf(v0.x * s); pk.h[1] = f2bf(v0.y * s);
            pk.h[2] = f2bf(v0.z * s); pk.h[3] = f2bf(v0.w * s);
            pk.h[4] = f2bf(v1.x * s); pk.h[5] = f2bf(v1.y * s);
            pk.h[6] = f2bf(v1.z * s); pk.h[7] = f2bf(v1.w * s);
            *reinterpret_cast<uint4*>(&As[row * 32 + quarter * 8]) = pk.v;
        }
        // B staging
        async16(gB0 + kt * 32, Bs + ca * 512);
        async16(gB1 + kt * 32, Bs + cb * 512);
        __syncthreads();
        bf16x8 af[4], bg[4];
        #pragma unroll
        for (int mi = 0; mi < 4; mi++)
            af[mi] = *reinterpret_cast<const bf16x8*>(
                &As[(wr*64 + mi*16 + t)*32 + q*8]);
        #pragma unroll
        for (int ni = 0; ni < 4; ni++)
            bg[ni] = *reinterpret_cast<const bf16x8*>(
                &Bs[(wc*64 + ni*16 + t)*32 + q*8]);
        #pragma unroll
        for (int mi = 0; mi < 4; mi++)
            #pragma unroll
            for (int ni = 0; ni < 4; ni++)
                acc[mi][ni] = __builtin_amdgcn_mfma_f32_16x16x32_bf16(
                    af[mi], bg[ni], acc[mi][ni], 0, 0, 0);
    }

    const bool outbf = (flags[0] != 0);
    #pragma unroll
    for (int mi = 0; mi < 4; mi++){
        #pragma unroll
        for (int i = 0; i < 4; i++){
            int m_l = wr*64 + mi*16 + q*4 + i;
            int node = node_of_slot[slotbase + m_l];
            bool ok = (node >= 0) && (z < 3 || labels[node] == k);
            if (!ok) continue;
            #pragma unroll
            for (int ni = 0; ni < 4; ni++){
                int n = n0 + wc*64 + ni*16 + t;
                float v = acc[mi][ni][i] + b2f[k * 1024 + n];
                size_t oi = (size_t)node * 1024 + n;
                if (outbf) ((u16*)dout)[oi] = f2bf(v);
                else       ((float*)dout)[oi] = v;
            }
        }
    }
}

// ---------------------------------------------------------------------------
extern "C" void kernel_launch(void* const* d_in, const int* in_sizes, int n_in,
                              void* d_out, int out_size, void* d_ws, size_t ws_size,
                              hipStream_t stream)
{
    constexpr int C = 256, R = 1024;
    constexpr int PPAD = 40064;          // 313 * 128
    constexpr int M1 = 3 * R;            // 3072 L1 rows (branch-major)
    constexpr int SLOTS = 512;           // 3*128 grouped + 128 overflow

    const void* x      = d_in[0];
    const void* masks  = d_in[1];
    const int*  labels = (const int*)d_in[2];
    (void)in_sizes; (void)n_in; (void)out_size; (void)ws_size;

    char* ws = (char*)d_ws;
    size_t off = 0;
    auto alloc = [&](size_t b)->size_t {
        size_t o = off; off += (b + 255) & ~(size_t)255; return o;
    };

    int*   flags   = (int*)  (ws + alloc(256));
    int*   slotmap = (int*)  (ws + alloc(384 * 4));
    int*   nodemap = (int*)  (ws + alloc(512 * 4));
    int*   ovfflag = (int*)  (ws + alloc(256));
    u16*   feat    = (u16*)  (ws + alloc((size_t)PPAD * C * 2));    // [p][c]
    u16*   B1T     = (u16*)  (ws + alloc((size_t)M1 * C * 2));      // [m][c]
    float* b1f     = (float*)(ws + alloc((size_t)M1 * 4));
    float* b2f     = (float*)(ws + alloc((size_t)M1 * 4));
    u16*   mfT     = (u16*)  (ws + alloc((size_t)SLOTS * PPAD * 2));// [slot][p]
    // contiguous zero region: sums3 | sumsOvf | counts
    float* sums3   = (float*)(ws + alloc((size_t)384 * 1024 * 4));
    float* sumsOvf = (float*)(ws + alloc((size_t)128 * M1 * 4));
    float* counts  = (float*)(ws + alloc((size_t)SLOTS * 4));
    u16*   W2T     = (u16*)  (ws + alloc((size_t)3 * R * R * 2));

    probe_and_perm<<<2, 320, 0, stream>>>(x, masks, flags, labels,
                                          slotmap, nodemap, ovfflag);
    hipMemsetAsync(mfT, 0, (size_t)SLOTS * PPAD * 2, stream);
    hipMemsetAsync(sums3, 0,
        (size_t)384 * 1024 * 4 + (size_t)128 * M1 * 4 + (size_t)SLOTS * 4, stream);

    prep_combo<<<10016 + 768 + 3072 + 12, 256, 0, stream>>>(
        x, d_in[3], d_in[7], d_in[11],           // W1
        d_in[5], d_in[9], d_in[13],              // W2
        d_in[4], d_in[8], d_in[12],              // b1
        d_in[6], d_in[10], d_in[14],             // b2
        feat, B1T, W2T, b1f, b2f, flags);

    trans_mask_count<<<dim3(PPAD / 128, 384 / 32), 256, 0, stream>>>(
        masks, mfT, slotmap, counts, flags);

    // fused L1 + mask-sum: 512 blocks = 2/CU x 256 CUs, one full round
    fused_l1_mask<0><<<512, 256, 0, stream>>>(
        B1T, feat, mfT, b1f, sums3, nullptr);
    // overflow path (skipped unless some label has > 128 nodes)
    fused_l1_mask<1><<<dim3(24, 8), 256, 0, stream>>>(
        B1T, feat, mfT, b1f, sumsOvf, ovfflag);

    // L2 + means + output gather, one launch
    l2_gemm<<<dim3(8, 1, 6), 256, 0, stream>>>(
        sums3, sumsOvf, counts, W2T, b2f, nodemap, labels, ovfflag,
        d_out, flags);
}